// Round 2
// baseline (526.194 us; speedup 1.0000x reference)
//
#include <hip/hip_runtime.h>
#include <hip/hip_bf16.h>

// Problem constants
#define NB 2
#define NS 2048
#define NH 16
#define ND 64
#define NHID 1024

typedef __attribute__((ext_vector_type(8))) short bf16x8;
typedef __attribute__((ext_vector_type(4))) short s16x4;
typedef __attribute__((ext_vector_type(4))) float f32x4;

__device__ inline short f2bf(float f) {
  __hip_bfloat16 h = __float2bfloat16(f);
  short s; __builtin_memcpy(&s, &h, 2); return s;
}

__device__ inline bf16x8 cvt8(const float* __restrict__ p) {
  float4 x = *(const float4*)p;
  float4 y = *(const float4*)(p + 4);
  bf16x8 r;
  r[0] = f2bf(x.x); r[1] = f2bf(x.y); r[2] = f2bf(x.z); r[3] = f2bf(x.w);
  r[4] = f2bf(y.x); r[5] = f2bf(y.y); r[6] = f2bf(y.z); r[7] = f2bf(y.w);
  return r;
}

__device__ inline float rmax16(float v) {
  v = fmaxf(v, __shfl_xor(v, 1));
  v = fmaxf(v, __shfl_xor(v, 2));
  v = fmaxf(v, __shfl_xor(v, 4));
  v = fmaxf(v, __shfl_xor(v, 8));
  return v;
}
__device__ inline float rsum16(float v) {
  v += __shfl_xor(v, 1);
  v += __shfl_xor(v, 2);
  v += __shfl_xor(v, 4);
  v += __shfl_xor(v, 8);
  return v;
}

// ---------------------------------------------------------------------------
// Kernel 0: convert fp32 weights -> bf16 in ws. Wo (1M), Wq/Wk/Wv (4096 each).
// ---------------------------------------------------------------------------
__global__ __launch_bounds__(256) void cvt_w(
    const float* __restrict__ Wq, const float* __restrict__ Wk,
    const float* __restrict__ Wv, const float* __restrict__ Wo,
    short* __restrict__ Wq_b, short* __restrict__ Wk_b,
    short* __restrict__ Wv_b, short* __restrict__ Wo_b)
{
  int i = (blockIdx.x * 256 + threadIdx.x) * 4;   // 0 .. 1060860 step 4
  const float* src; short* dst; int off;
  if (i < 1048576)      { src = Wo; dst = Wo_b; off = i; }
  else {
    int j = i - 1048576;
    if (j < 4096)       { src = Wq; dst = Wq_b; off = j; }
    else if (j < 8192)  { src = Wk; dst = Wk_b; off = j - 4096; }
    else                { src = Wv; dst = Wv_b; off = j - 8192; }
  }
  float4 v = *(const float4*)(src + off);
  s16x4 o;
  o[0] = f2bf(v.x); o[1] = f2bf(v.y); o[2] = f2bf(v.z); o[3] = f2bf(v.w);
  *(s16x4*)(dst + off) = o;
}

// ---------------------------------------------------------------------------
// Kernel 1: QKV projection. Three GEMMs [B*S*H, 64] x [64,64]^T + bias.
// fp32 activations converted inline; bf16 weights from ws.
// Writes Q,K as [BH, S, 64] bf16; V transposed as [BH, 64, S] bf16.
// ---------------------------------------------------------------------------
__global__ __launch_bounds__(64) void qkv_proj(
    const float* __restrict__ qin, const float* __restrict__ kin,
    const float* __restrict__ vin,
    const short* __restrict__ Wq_b, const float* __restrict__ bq,
    const short* __restrict__ Wk_b, const float* __restrict__ bk,
    const short* __restrict__ Wv_b, const float* __restrict__ bv,
    short* __restrict__ Qws, short* __restrict__ Kws, short* __restrict__ Vt)
{
  const int lane = threadIdx.x;
  const int c = lane & 15, qq = lane >> 4;
  const int rowbase = blockIdx.x * 16;          // token-head rows (b*S+s)*16+h
  const int aoff = (rowbase + c) * 64 + qq * 8;

#pragma unroll
  for (int m = 0; m < 3; ++m) {
    const float* X  = (m == 0) ? qin  : (m == 1) ? kin  : vin;
    const short* W  = (m == 0) ? Wq_b : (m == 1) ? Wk_b : Wv_b;
    const float* bb = (m == 0) ? bq   : (m == 1) ? bk   : bv;

    bf16x8 a0 = cvt8(X + aoff);
    bf16x8 a1 = cvt8(X + aoff + 32);

    f32x4 acc[4];
#pragma unroll
    for (int nt = 0; nt < 4; ++nt) {
      f32x4 z = {0.f, 0.f, 0.f, 0.f};
      const short* wp = W + (nt * 16 + c) * 64 + qq * 8;
      bf16x8 b0 = *(const bf16x8*)(wp);
      bf16x8 b1 = *(const bf16x8*)(wp + 32);
      z = __builtin_amdgcn_mfma_f32_16x16x32_bf16(a0, b0, z, 0, 0, 0);
      z = __builtin_amdgcn_mfma_f32_16x16x32_bf16(a1, b1, z, 0, 0, 0);
      acc[nt] = z;
    }

#pragma unroll
    for (int nt = 0; nt < 4; ++nt) {
#pragma unroll
      for (int r = 0; r < 4; ++r) {
        int row = rowbase + qq * 4 + r;   // (b*S+s)*16 + h
        int h = row & 15;
        int s = (row >> 4) & (NS - 1);
        int b = row >> 15;
        int d = nt * 16 + c;
        short o = f2bf(acc[nt][r] + bb[d]);
        int bh = b * NH + h;
        if (m == 0)      Qws[(bh * NS + s) * 64 + d] = o;
        else if (m == 1) Kws[(bh * NS + s) * 64 + d] = o;
        else             Vt[(bh * 64 + d) * NS + s] = o;
      }
    }
  }
}

// ---------------------------------------------------------------------------
// Kernel 2: pack mask int32 [B,1,S,S] -> bitwords [B*S, S/32]
// ---------------------------------------------------------------------------
__global__ __launch_bounds__(256) void pack_mask(const int* __restrict__ mask,
                                                 unsigned* __restrict__ mp)
{
  int idx = blockIdx.x * 256 + threadIdx.x;     // 0 .. B*S*(S/32)-1
  const int4* src = (const int4*)(mask + (long)idx * 32);
  unsigned w = 0;
#pragma unroll
  for (int i = 0; i < 8; ++i) {
    int4 v = src[i];
    w |= (v.x != 0 ? 1u : 0u) << (i * 4 + 0);
    w |= (v.y != 0 ? 1u : 0u) << (i * 4 + 1);
    w |= (v.z != 0 ? 1u : 0u) << (i * 4 + 2);
    w |= (v.w != 0 ? 1u : 0u) << (i * 4 + 3);
  }
  mp[idx] = w;
}

// ---------------------------------------------------------------------------
// Kernel 3: flash attention. Block = 4 waves; wave owns 16 q-rows of one (b,h).
// ---------------------------------------------------------------------------
__global__ __launch_bounds__(256) void attn(
    const short* __restrict__ Qws, const short* __restrict__ Kws,
    const short* __restrict__ Vt, const unsigned* __restrict__ Mp,
    short* __restrict__ AO)
{
  __shared__ __align__(16) short ldsP[4][16][72];   // per-wave P tile, padded
  const int tid = threadIdx.x;
  const int w = tid >> 6, lane = tid & 63;
  const int c = lane & 15, qq = lane >> 4;
  const int bh = blockIdx.x >> 5;                    // 0..31
  const int qtile = blockIdx.x & 31;
  const int b = bh >> 4, h = bh & 15;
  const int qbase = qtile * 64 + w * 16;

  const short* Qp = Qws + bh * (NS * 64);
  const short* Kp = Kws + bh * (NS * 64);
  const short* Vp = Vt + bh * (64 * NS);
  const unsigned* mrow = Mp + b * (NS * (NS / 32));

  // Q fragments (A layout): row = lane&15, k = (lane>>4)*8 + j
  bf16x8 aq0 = *(const bf16x8*)(Qp + (qbase + c) * 64 + qq * 8);
  bf16x8 aq1 = *(const bf16x8*)(Qp + (qbase + c) * 64 + 32 + qq * 8);

  float m_i[4], l_i[4];
  f32x4 O[4];
#pragma unroll
  for (int r = 0; r < 4; ++r) { m_i[r] = -1e30f; l_i[r] = 0.f; }
#pragma unroll
  for (int dt = 0; dt < 4; ++dt) { f32x4 z = {0.f, 0.f, 0.f, 0.f}; O[dt] = z; }

  for (int kt = 0; kt < NS / 64; ++kt) {
    const int kbase = kt * 64;

    // QK^T: 4 n-tiles x 2 k-steps
    f32x4 st[4];
#pragma unroll
    for (int nt = 0; nt < 4; ++nt) {
      f32x4 z = {0.f, 0.f, 0.f, 0.f};
      const short* kp = Kp + (kbase + nt * 16 + c) * 64 + qq * 8;
      bf16x8 b0 = *(const bf16x8*)(kp);
      bf16x8 b1 = *(const bf16x8*)(kp + 32);
      z = __builtin_amdgcn_mfma_f32_16x16x32_bf16(aq0, b0, z, 0, 0, 0);
      z = __builtin_amdgcn_mfma_f32_16x16x32_bf16(aq1, b1, z, 0, 0, 0);
      st[nt] = z;
    }

    // mask + scale + online softmax (row r lives in the 16 lanes of group qq)
    float p[4][4];
    float alpha[4];
#pragma unroll
    for (int r = 0; r < 4; ++r) {
      const int row = qbase + qq * 4 + r;
      unsigned mw0 = mrow[row * (NS / 32) + kt * 2];
      unsigned mw1 = mrow[row * (NS / 32) + kt * 2 + 1];
      float tmax = -1e30f;
#pragma unroll
      for (int nt = 0; nt < 4; ++nt) {
        unsigned wsel = (nt & 2) ? mw1 : mw0;
        int sh = ((nt & 1) << 4) + c;
        bool keep = (wsel >> sh) & 1u;
        float s = keep ? st[nt][r] * 0.03125f : -1e30f;
        p[nt][r] = s;
        tmax = fmaxf(tmax, s);
      }
      tmax = rmax16(tmax);
      float mnew = fmaxf(m_i[r], tmax);
      alpha[r] = __expf(m_i[r] - mnew);
      m_i[r] = mnew;
      float rs = 0.f;
#pragma unroll
      for (int nt = 0; nt < 4; ++nt) {
        float e = __expf(p[nt][r] - mnew);
        p[nt][r] = e;
        rs += e;
      }
      rs = rsum16(rs);
      l_i[r] = l_i[r] * alpha[r] + rs;
    }
#pragma unroll
    for (int dt = 0; dt < 4; ++dt)
#pragma unroll
      for (int r = 0; r < 4; ++r)
        O[dt][r] *= alpha[r];

    // P: C/D layout -> LDS -> A layout
    __syncthreads();
#pragma unroll
    for (int nt = 0; nt < 4; ++nt)
#pragma unroll
      for (int r = 0; r < 4; ++r)
        ldsP[w][qq * 4 + r][nt * 16 + c] = f2bf(p[nt][r]);
    __syncthreads();

    // PV: O += P @ V  (B-frags from transposed V, 16B contiguous)
#pragma unroll
    for (int ks = 0; ks < 2; ++ks) {
      bf16x8 ap = *(const bf16x8*)(&ldsP[w][c][ks * 32 + qq * 8]);
#pragma unroll
      for (int dt = 0; dt < 4; ++dt) {
        bf16x8 bv_ = *(const bf16x8*)(Vp + (dt * 16 + c) * NS + kbase + ks * 32 + qq * 8);
        O[dt] = __builtin_amdgcn_mfma_f32_16x16x32_bf16(ap, bv_, O[dt], 0, 0, 0);
      }
    }
  }

  // epilogue: normalize, store attention output token-major [B,S,HID] bf16
#pragma unroll
  for (int r = 0; r < 4; ++r) l_i[r] = 1.0f / l_i[r];
#pragma unroll
  for (int dt = 0; dt < 4; ++dt)
#pragma unroll
    for (int r = 0; r < 4; ++r) {
      int row = qbase + qq * 4 + r;
      int col = h * 64 + dt * 16 + c;
      AO[(b * NS + row) * NHID + col] = f2bf(O[dt][r] * l_i[r]);
    }
}

// ---------------------------------------------------------------------------
// Kernel 4: output projection [4096,1024] x Wo^T + bo -> fp32 out.
// ---------------------------------------------------------------------------
__global__ __launch_bounds__(64) void oproj(
    const short* __restrict__ X, const short* __restrict__ Wo_b,
    const float* __restrict__ bo, float* __restrict__ out)
{
  const int lane = threadIdx.x;
  const int c = lane & 15, qq = lane >> 4;
  const int rt = blockIdx.x;   // 0..255 row tiles of 16
  const int cg = blockIdx.y;   // 0..15 col groups of 64

  f32x4 acc[4];
#pragma unroll
  for (int nt = 0; nt < 4; ++nt) { f32x4 z = {0.f, 0.f, 0.f, 0.f}; acc[nt] = z; }

  const short* xp = X + (rt * 16 + c) * NHID + qq * 8;
  for (int kb = 0; kb < NHID / 32; ++kb) {
    bf16x8 a = *(const bf16x8*)(xp + kb * 32);
#pragma unroll
    for (int nt = 0; nt < 4; ++nt) {
      bf16x8 bw = *(const bf16x8*)(Wo_b + (cg * 64 + nt * 16 + c) * NHID + kb * 32 + qq * 8);
      acc[nt] = __builtin_amdgcn_mfma_f32_16x16x32_bf16(a, bw, acc[nt], 0, 0, 0);
    }
  }

#pragma unroll
  for (int nt = 0; nt < 4; ++nt) {
    int col = cg * 64 + nt * 16 + c;
    float bias = bo[col];
#pragma unroll
    for (int r = 0; r < 4; ++r)
      out[(rt * 16 + qq * 4 + r) * NHID + col] = acc[nt][r] + bias;
  }
}

// ---------------------------------------------------------------------------
extern "C" void kernel_launch(void* const* d_in, const int* in_sizes, int n_in,
                              void* d_out, int out_size, void* d_ws, size_t ws_size,
                              hipStream_t stream) {
  const float* qin = (const float*)d_in[0];
  const float* kin = (const float*)d_in[1];
  const float* vin = (const float*)d_in[2];
  const int*  mask = (const int*)d_in[3];
  const float* Wq = (const float*)d_in[4];
  const float* bq = (const float*)d_in[5];
  const float* Wk = (const float*)d_in[6];
  const float* bk = (const float*)d_in[7];
  const float* Wv = (const float*)d_in[8];
  const float* bv = (const float*)d_in[9];
  const float* Wo = (const float*)d_in[10];
  const float* bo = (const float*)d_in[11];
  float* out = (float*)d_out;

  char* ws = (char*)d_ws;
  short* Qws = (short*)(ws);                           // 8 MB  [BH,S,64]
  short* Kws = (short*)(ws + (size_t)(8 << 20));       // 8 MB  [BH,S,64]
  short* Vt  = (short*)(ws + (size_t)(16 << 20));      // 8 MB  [BH,64,S]
  short* AO  = (short*)(ws + (size_t)(24 << 20));      // 8 MB  [B,S,HID]
  unsigned* Mp = (unsigned*)(ws + (size_t)(32 << 20)); // 1 MB packed mask
  short* Wo_b = (short*)(ws + (size_t)(33 << 20));     // 2 MB
  short* Wq_b = (short*)(ws + (size_t)(35 << 20));     // 8 KB
  short* Wk_b = (short*)(ws + (size_t)(35 << 20) + 8192);
  short* Wv_b = (short*)(ws + (size_t)(35 << 20) + 16384);

  cvt_w<<<1036, 256, 0, stream>>>(Wq, Wk, Wv, Wo, Wq_b, Wk_b, Wv_b, Wo_b);
  qkv_proj<<<(NB * NS * NH) / 16, 64, 0, stream>>>(qin, kin, vin, Wq_b, bq, Wk_b,
                                                   bk, Wv_b, bv, Qws, Kws, Vt);
  pack_mask<<<(NB * NS * (NS / 32)) / 256, 256, 0, stream>>>(mask, Mp);
  attn<<<(NB * NH) * (NS / 64), 256, 0, stream>>>(Qws, Kws, Vt, Mp, AO);
  oproj<<<dim3((NB * NS) / 16, NHID / 64), 64, 0, stream>>>(AO, Wo_b, bo, out);
}

// Round 3
// 470.068 us; speedup vs baseline: 1.1194x; 1.1194x over previous
//
#include <hip/hip_runtime.h>
#include <hip/hip_bf16.h>

// Problem constants
#define NB 2
#define NS 2048
#define NH 16
#define ND 64
#define NHID 1024

typedef __attribute__((ext_vector_type(8))) short bf16x8;
typedef __attribute__((ext_vector_type(4))) short s16x4;
typedef __attribute__((ext_vector_type(4))) float f32x4;

__device__ inline short f2bf(float f) {
  __hip_bfloat16 h = __float2bfloat16(f);
  short s; __builtin_memcpy(&s, &h, 2); return s;
}

__device__ inline bf16x8 cvt8(const float* __restrict__ p) {
  float4 x = *(const float4*)p;
  float4 y = *(const float4*)(p + 4);
  bf16x8 r;
  r[0] = f2bf(x.x); r[1] = f2bf(x.y); r[2] = f2bf(x.z); r[3] = f2bf(x.w);
  r[4] = f2bf(y.x); r[5] = f2bf(y.y); r[6] = f2bf(y.z); r[7] = f2bf(y.w);
  return r;
}

__device__ inline float rsum16(float v) {
  v += __shfl_xor(v, 1);
  v += __shfl_xor(v, 2);
  v += __shfl_xor(v, 4);
  v += __shfl_xor(v, 8);
  return v;
}

// ---------------------------------------------------------------------------
// Kernel 0: convert fp32 weights -> bf16 in ws.
// ---------------------------------------------------------------------------
__global__ __launch_bounds__(256) void cvt_w(
    const float* __restrict__ Wq, const float* __restrict__ Wk,
    const float* __restrict__ Wv, const float* __restrict__ Wo,
    short* __restrict__ Wq_b, short* __restrict__ Wk_b,
    short* __restrict__ Wv_b, short* __restrict__ Wo_b)
{
  int i = (blockIdx.x * 256 + threadIdx.x) * 4;
  const float* src; short* dst; int off;
  if (i < 1048576)      { src = Wo; dst = Wo_b; off = i; }
  else {
    int j = i - 1048576;
    if (j < 4096)       { src = Wq; dst = Wq_b; off = j; }
    else if (j < 8192)  { src = Wk; dst = Wk_b; off = j - 4096; }
    else                { src = Wv; dst = Wv_b; off = j - 8192; }
  }
  float4 v = *(const float4*)(src + off);
  s16x4 o;
  o[0] = f2bf(v.x); o[1] = f2bf(v.y); o[2] = f2bf(v.z); o[3] = f2bf(v.w);
  *(s16x4*)(dst + off) = o;
}

// ---------------------------------------------------------------------------
// Kernel 1: Q,K projection. Block = 1 token (16 heads), 64 threads (1 wave).
// LDS transpose -> coalesced 128B-line stores into [BH,S,64] bf16.
// No barriers: LDS is wave-private, compiler orders via lgkmcnt.
// ---------------------------------------------------------------------------
__global__ __launch_bounds__(64) void qk_proj(
    const float* __restrict__ qin, const float* __restrict__ kin,
    const short* __restrict__ Wq_b, const float* __restrict__ bq,
    const short* __restrict__ Wk_b, const float* __restrict__ bk,
    short* __restrict__ Qws, short* __restrict__ Kws)
{
  __shared__ __align__(16) short ldsT[16][72];
  const int lane = threadIdx.x;
  const int c = lane & 15, qq = lane >> 4;
  const int t = blockIdx.x;                 // b*S + s
  const int b = t >> 11, s = t & (NS - 1);
  const int aoff = (t * 16 + c) * 64 + qq * 8;
  const int row0 = lane >> 3, inner = lane & 7;

#pragma unroll
  for (int m = 0; m < 2; ++m) {
    const float* X  = (m == 0) ? qin  : kin;
    const short* W  = (m == 0) ? Wq_b : Wk_b;
    const float* bb = (m == 0) ? bq   : bk;
    short* dst      = (m == 0) ? Qws  : Kws;

    bf16x8 a0 = cvt8(X + aoff);
    bf16x8 a1 = cvt8(X + aoff + 32);

#pragma unroll
    for (int nt = 0; nt < 4; ++nt) {
      f32x4 z = {0.f, 0.f, 0.f, 0.f};
      const short* wp = W + (nt * 16 + c) * 64 + qq * 8;
      bf16x8 b0 = *(const bf16x8*)(wp);
      bf16x8 b1 = *(const bf16x8*)(wp + 32);
      z = __builtin_amdgcn_mfma_f32_16x16x32_bf16(a0, b0, z, 0, 0, 0);
      z = __builtin_amdgcn_mfma_f32_16x16x32_bf16(a1, b1, z, 0, 0, 0);
      float bias = bb[nt * 16 + c];
#pragma unroll
      for (int r = 0; r < 4; ++r)           // C row = head h' = qq*4+r
        ldsT[qq * 4 + r][nt * 16 + c] = f2bf(z[r] + bias);
    }

    // coalesced readback: 2 x b128 + 2 stores (8 full 128B lines each)
    bf16x8 v0 = *(const bf16x8*)&ldsT[row0][inner * 8];
    bf16x8 v1 = *(const bf16x8*)&ldsT[row0 + 8][inner * 8];
    int bh0 = b * NH + row0, bh1 = b * NH + row0 + 8;
    *(bf16x8*)(dst + (bh0 * NS + s) * 64 + inner * 8) = v0;
    *(bf16x8*)(dst + (bh1 * NS + s) * 64 + inner * 8) = v1;
  }
}

// ---------------------------------------------------------------------------
// Kernel 1b: V projection + transpose, fused. Block = (head, 64 tokens).
// Gathers fp32 V rows, MFMA-projects, transposes 64x64 in LDS, writes
// Vt [BH,64,S] with coalesced full-line stores.
// ---------------------------------------------------------------------------
__global__ __launch_bounds__(64) void vproj(
    const float* __restrict__ vin, const short* __restrict__ Wv_b,
    const float* __restrict__ bv, short* __restrict__ Vt)
{
  __shared__ __align__(16) short ldsVT[64][72];   // [d][token], stride 144B
  const int lane = threadIdx.x;
  const int c = lane & 15, qq = lane >> 4;
  const int bh = blockIdx.x >> 5;
  const int stile = blockIdx.x & 31;
  const int b = bh >> 4, h = bh & 15;
  const int sb = stile * 64;

  bf16x8 wv[8];
  float bias[4];
#pragma unroll
  for (int nt = 0; nt < 4; ++nt) {
    const short* wp = Wv_b + (nt * 16 + c) * 64 + qq * 8;
    wv[nt * 2]     = *(const bf16x8*)(wp);
    wv[nt * 2 + 1] = *(const bf16x8*)(wp + 32);
    bias[nt] = bv[nt * 16 + c];
  }

#pragma unroll
  for (int g = 0; g < 4; ++g) {
    const float* ap = vin + ((size_t)((b * NS + sb + 16 * g + c) * 16 + h)) * 64 + qq * 8;
    bf16x8 a0 = cvt8(ap);
    bf16x8 a1 = cvt8(ap + 32);
#pragma unroll
    for (int nt = 0; nt < 4; ++nt) {
      f32x4 z = {0.f, 0.f, 0.f, 0.f};
      z = __builtin_amdgcn_mfma_f32_16x16x32_bf16(a0, wv[nt * 2], z, 0, 0, 0);
      z = __builtin_amdgcn_mfma_f32_16x16x32_bf16(a1, wv[nt * 2 + 1], z, 0, 0, 0);
      // C rows = tokens qq*4+r -> pack 4 adjacent tokens, one b64 write
      ushort4 u;
      u.x = (unsigned short)f2bf(z[0] + bias[nt]);
      u.y = (unsigned short)f2bf(z[1] + bias[nt]);
      u.z = (unsigned short)f2bf(z[2] + bias[nt]);
      u.w = (unsigned short)f2bf(z[3] + bias[nt]);
      *(ushort4*)&ldsVT[nt * 16 + c][16 * g + qq * 4] = u;
    }
  }

  // coalesced out: row d contiguous in tokens
#pragma unroll
  for (int j = 0; j < 8; ++j) {
    int d = (lane >> 3) + 8 * j;
    bf16x8 o = *(const bf16x8*)&ldsVT[d][(lane & 7) * 8];
    *(bf16x8*)(Vt + ((size_t)(bh * 64 + d)) * NS + sb + (lane & 7) * 8) = o;
  }
}

// ---------------------------------------------------------------------------
// Kernel 2: pack mask int32 [B,1,S,S] -> bitwords [B*S, S/32]
// ---------------------------------------------------------------------------
__global__ __launch_bounds__(256) void pack_mask(const int* __restrict__ mask,
                                                 unsigned* __restrict__ mp)
{
  int idx = blockIdx.x * 256 + threadIdx.x;
  const int4* src = (const int4*)(mask + (long)idx * 32);
  unsigned w = 0;
#pragma unroll
  for (int i = 0; i < 8; ++i) {
    int4 v = src[i];
    w |= (v.x != 0 ? 1u : 0u) << (i * 4 + 0);
    w |= (v.y != 0 ? 1u : 0u) << (i * 4 + 1);
    w |= (v.z != 0 ? 1u : 0u) << (i * 4 + 2);
    w |= (v.w != 0 ? 1u : 0u) << (i * 4 + 3);
  }
  mp[idx] = w;
}

// ---------------------------------------------------------------------------
// Kernel 3: flash attention, no-max softmax (scores/32 are O(1): exp safe).
// Block = 4 independent waves, NO barriers. K-frags + mask prefetched one
// iteration ahead; per-lane partial row sums, single cross-lane reduce at end.
// ---------------------------------------------------------------------------
__global__ __launch_bounds__(256) void attn(
    const short* __restrict__ Qws, const short* __restrict__ Kws,
    const short* __restrict__ Vt, const unsigned* __restrict__ Mp,
    short* __restrict__ AO)
{
  __shared__ __align__(16) short ldsP[4][16][72];
  const int tid = threadIdx.x;
  const int w = tid >> 6, lane = tid & 63;
  const int c = lane & 15, qq = lane >> 4;
  const int bh = blockIdx.x >> 5;
  const int qtile = blockIdx.x & 31;
  const int b = bh >> 4, h = bh & 15;
  const int qbase = qtile * 64 + w * 16;

  const short* Qp = Qws + (size_t)bh * (NS * 64);
  const short* Kp = Kws + (size_t)bh * (NS * 64);
  const short* Vp = Vt + (size_t)bh * (64 * NS);
  const unsigned* mrow = Mp + (size_t)b * (NS * (NS / 32));

  // exp(x/32) = exp2(x * log2(e)/32)
  const float C2 = 0.045084220f;

  bf16x8 aq0 = *(const bf16x8*)(Qp + (qbase + c) * 64 + qq * 8);
  bf16x8 aq1 = *(const bf16x8*)(Qp + (qbase + c) * 64 + 32 + qq * 8);

  float lsum[4];
  f32x4 O[4];
#pragma unroll
  for (int r = 0; r < 4; ++r) lsum[r] = 0.f;
#pragma unroll
  for (int dt = 0; dt < 4; ++dt) { f32x4 z = {0.f, 0.f, 0.f, 0.f}; O[dt] = z; }

  // prefetch kt=0
  bf16x8 kf[8];
#pragma unroll
  for (int nt = 0; nt < 4; ++nt) {
    const short* kp = Kp + (nt * 16 + c) * 64 + qq * 8;
    kf[nt * 2]     = *(const bf16x8*)(kp);
    kf[nt * 2 + 1] = *(const bf16x8*)(kp + 32);
  }
  uint2 mw[4];
#pragma unroll
  for (int r = 0; r < 4; ++r)
    mw[r] = *(const uint2*)(mrow + (qbase + qq * 4 + r) * (NS / 32));

  for (int kt = 0; kt < NS / 64; ++kt) {
    const int kbase = kt * 64;

    // QK^T with prefetched K
    f32x4 st[4];
#pragma unroll
    for (int nt = 0; nt < 4; ++nt) {
      f32x4 z = {0.f, 0.f, 0.f, 0.f};
      z = __builtin_amdgcn_mfma_f32_16x16x32_bf16(aq0, kf[nt * 2], z, 0, 0, 0);
      z = __builtin_amdgcn_mfma_f32_16x16x32_bf16(aq1, kf[nt * 2 + 1], z, 0, 0, 0);
      st[nt] = z;
    }

    // prefetch next K + mask (harmless over-read on last iter; ws is allocated)
    bf16x8 kn[8];
#pragma unroll
    for (int nt = 0; nt < 4; ++nt) {
      const short* kp = Kp + (kbase + 64 + nt * 16 + c) * 64 + qq * 8;
      kn[nt * 2]     = *(const bf16x8*)(kp);
      kn[nt * 2 + 1] = *(const bf16x8*)(kp + 32);
    }
    uint2 mn[4];
#pragma unroll
    for (int r = 0; r < 4; ++r)
      mn[r] = *(const uint2*)(mrow + (qbase + qq * 4 + r) * (NS / 32) + kt * 2 + 2);

    // V loads for this tile (latency hidden under exp/LDS below)
    bf16x8 vf[8];
#pragma unroll
    for (int ks = 0; ks < 2; ++ks)
#pragma unroll
      for (int dt = 0; dt < 4; ++dt)
        vf[ks * 4 + dt] = *(const bf16x8*)(Vp + (dt * 16 + c) * NS + kbase + ks * 32 + qq * 8);

    // masked exp (no max, no rescale); P -> LDS (wave-private, no barrier)
#pragma unroll
    for (int r = 0; r < 4; ++r) {
#pragma unroll
      for (int nt = 0; nt < 4; ++nt) {
        unsigned wsel = (nt & 2) ? mw[r].y : mw[r].x;
        int sh = ((nt & 1) << 4) + c;
        float bit = (float)((wsel >> sh) & 1u);
        float e = __builtin_amdgcn_exp2f(st[nt][r] * C2) * bit;
        lsum[r] += e;
        ldsP[w][qq * 4 + r][nt * 16 + c] = f2bf(e);
      }
    }

    // PV
#pragma unroll
    for (int ks = 0; ks < 2; ++ks) {
      bf16x8 ap = *(const bf16x8*)(&ldsP[w][c][ks * 32 + qq * 8]);
#pragma unroll
      for (int dt = 0; dt < 4; ++dt)
        O[dt] = __builtin_amdgcn_mfma_f32_16x16x32_bf16(ap, vf[ks * 4 + dt], O[dt], 0, 0, 0);
    }

    // rotate prefetch
#pragma unroll
    for (int i = 0; i < 8; ++i) kf[i] = kn[i];
#pragma unroll
    for (int r = 0; r < 4; ++r) mw[r] = mn[r];
  }

  // cross-lane row sums (once), normalize, store token-major [B,S,HID] bf16
  float inv[4];
#pragma unroll
  for (int r = 0; r < 4; ++r) inv[r] = 1.0f / fmaxf(rsum16(lsum[r]), 1e-30f);
#pragma unroll
  for (int dt = 0; dt < 4; ++dt)
#pragma unroll
    for (int r = 0; r < 4; ++r) {
      int row = qbase + qq * 4 + r;
      int col = h * 64 + dt * 16 + c;
      AO[((size_t)(b * NS + row)) * NHID + col] = f2bf(O[dt][r] * inv[r]);
    }
}

// ---------------------------------------------------------------------------
// Kernel 4: output projection [4096,1024] x Wo^T + bo -> fp32 out.
// Block = 4 waves, 64 rows x 128 cols; waves share Wo lines via L1.
// ---------------------------------------------------------------------------
__global__ __launch_bounds__(256) void oproj(
    const short* __restrict__ X, const short* __restrict__ Wo_b,
    const float* __restrict__ bo, float* __restrict__ out)
{
  const int tid = threadIdx.x;
  const int w = tid >> 6, lane = tid & 63;
  const int c = lane & 15, qq = lane >> 4;
  const int rt = blockIdx.x;   // 64 row tiles of 64
  const int cg = blockIdx.y;   // 8 col groups of 128
  const int row0 = rt * 64 + w * 16;

  f32x4 acc[8];
#pragma unroll
  for (int nt = 0; nt < 8; ++nt) { f32x4 z = {0.f, 0.f, 0.f, 0.f}; acc[nt] = z; }

  const short* xp = X + (row0 + c) * NHID + qq * 8;
  for (int kb = 0; kb < NHID / 32; ++kb) {
    bf16x8 a = *(const bf16x8*)(xp + kb * 32);
#pragma unroll
    for (int nt = 0; nt < 8; ++nt) {
      bf16x8 bw = *(const bf16x8*)(Wo_b + (cg * 128 + nt * 16 + c) * NHID + kb * 32 + qq * 8);
      acc[nt] = __builtin_amdgcn_mfma_f32_16x16x32_bf16(a, bw, acc[nt], 0, 0, 0);
    }
  }

#pragma unroll
  for (int nt = 0; nt < 8; ++nt) {
    int col = cg * 128 + nt * 16 + c;
    float bias = bo[col];
#pragma unroll
    for (int r = 0; r < 4; ++r)
      out[(size_t)(row0 + qq * 4 + r) * NHID + col] = acc[nt][r] + bias;
  }
}

// ---------------------------------------------------------------------------
extern "C" void kernel_launch(void* const* d_in, const int* in_sizes, int n_in,
                              void* d_out, int out_size, void* d_ws, size_t ws_size,
                              hipStream_t stream) {
  const float* qin = (const float*)d_in[0];
  const float* kin = (const float*)d_in[1];
  const float* vin = (const float*)d_in[2];
  const int*  mask = (const int*)d_in[3];
  const float* Wq = (const float*)d_in[4];
  const float* bq = (const float*)d_in[5];
  const float* Wk = (const float*)d_in[6];
  const float* bk = (const float*)d_in[7];
  const float* Wv = (const float*)d_in[8];
  const float* bv = (const float*)d_in[9];
  const float* Wo = (const float*)d_in[10];
  const float* bo = (const float*)d_in[11];
  float* out = (float*)d_out;

  char* ws = (char*)d_ws;
  short* Qws = (short*)(ws);                           // 8 MB  [BH,S,64]
  short* Kws = (short*)(ws + (size_t)(8 << 20));       // 8 MB  [BH,S,64]
  short* Vt  = (short*)(ws + (size_t)(16 << 20));      // 8 MB  [BH,64,S]
  short* AO  = (short*)(ws + (size_t)(24 << 20));      // 8 MB  [B,S,HID]
  unsigned* Mp = (unsigned*)(ws + (size_t)(32 << 20)); // 1 MB packed mask
  short* Wo_b = (short*)(ws + (size_t)(33 << 20));     // 2 MB
  short* Wq_b = (short*)(ws + (size_t)(35 << 20));     // 8 KB
  short* Wk_b = (short*)(ws + (size_t)(35 << 20) + 8192);
  short* Wv_b = (short*)(ws + (size_t)(35 << 20) + 16384);

  cvt_w<<<1036, 256, 0, stream>>>(Wq, Wk, Wv, Wo, Wq_b, Wk_b, Wv_b, Wo_b);
  qk_proj<<<NB * NS, 64, 0, stream>>>(qin, kin, Wq_b, bq, Wk_b, bk, Qws, Kws);
  vproj<<<(NB * NH) * (NS / 64), 64, 0, stream>>>(vin, Wv_b, bv, Vt);
  pack_mask<<<(NB * NS * (NS / 32)) / 256, 256, 0, stream>>>(mask, Mp);
  attn<<<(NB * NH) * (NS / 64), 256, 0, stream>>>(Qws, Kws, Vt, Mp, AO);
  oproj<<<dim3(64, 8), 256, 0, stream>>>(AO, Wo_b, bo, out);
}

// Round 4
// 306.974 us; speedup vs baseline: 1.7141x; 1.5313x over previous
//
#include <hip/hip_runtime.h>
#include <hip/hip_bf16.h>

#define NB 2
#define NS 2048
#define NH 16
#define ND 64
#define NHID 1024

typedef __attribute__((ext_vector_type(8))) short bf16x8;
typedef __attribute__((ext_vector_type(4))) short s16x4;
typedef __attribute__((ext_vector_type(4))) float f32x4;

typedef __attribute__((address_space(3))) unsigned int lds_u32;
typedef __attribute__((address_space(1))) unsigned int glb_u32;

__device__ inline void gl_lds16(const void* g, void* l) {
  // async global->LDS, 16B/lane; LDS dest = wave-uniform base + lane*16
  __builtin_amdgcn_global_load_lds((const glb_u32*)g, (lds_u32*)l, 16, 0, 0);
}

__device__ inline short f2bf(float f) {
  __hip_bfloat16 h = __float2bfloat16(f);
  short s; __builtin_memcpy(&s, &h, 2); return s;
}

__device__ inline bf16x8 cvt8(const float* __restrict__ p) {
  float4 x = *(const float4*)p;
  float4 y = *(const float4*)(p + 4);
  bf16x8 r;
  r[0] = f2bf(x.x); r[1] = f2bf(x.y); r[2] = f2bf(x.z); r[3] = f2bf(x.w);
  r[4] = f2bf(y.x); r[5] = f2bf(y.y); r[6] = f2bf(y.z); r[7] = f2bf(y.w);
  return r;
}

__device__ inline float rsum16(float v) {
  v += __shfl_xor(v, 1);
  v += __shfl_xor(v, 2);
  v += __shfl_xor(v, 4);
  v += __shfl_xor(v, 8);
  return v;
}

// ---------------------------------------------------------------------------
// Kernel 0: fp32 weights -> bf16 in ws
// ---------------------------------------------------------------------------
__global__ __launch_bounds__(256) void cvt_w(
    const float* __restrict__ Wq, const float* __restrict__ Wk,
    const float* __restrict__ Wv, const float* __restrict__ Wo,
    short* __restrict__ Wq_b, short* __restrict__ Wk_b,
    short* __restrict__ Wv_b, short* __restrict__ Wo_b)
{
  int i = (blockIdx.x * 256 + threadIdx.x) * 4;
  const float* src; short* dst; int off;
  if (i < 1048576)      { src = Wo; dst = Wo_b; off = i; }
  else {
    int j = i - 1048576;
    if (j < 4096)       { src = Wq; dst = Wq_b; off = j; }
    else if (j < 8192)  { src = Wk; dst = Wk_b; off = j - 4096; }
    else                { src = Wv; dst = Wv_b; off = j - 8192; }
  }
  float4 v = *(const float4*)(src + off);
  s16x4 o;
  o[0] = f2bf(v.x); o[1] = f2bf(v.y); o[2] = f2bf(v.z); o[3] = f2bf(v.w);
  *(s16x4*)(dst + off) = o;
}

// ---------------------------------------------------------------------------
// Kernel 1: Q,K projection. Block = 4 waves, wave = 1 token (16 heads).
// ---------------------------------------------------------------------------
__global__ __launch_bounds__(256) void qk_proj(
    const float* __restrict__ qin, const float* __restrict__ kin,
    const short* __restrict__ Wq_b, const float* __restrict__ bq,
    const short* __restrict__ Wk_b, const float* __restrict__ bk,
    short* __restrict__ Qws, short* __restrict__ Kws)
{
  __shared__ __align__(16) short ldsT[4][16][72];
  const int tid = threadIdx.x;
  const int w = tid >> 6, lane = tid & 63;
  const int c = lane & 15, qq = lane >> 4;
  const int t = blockIdx.x * 4 + w;         // b*S + s
  const int b = t >> 11, s = t & (NS - 1);
  const int aoff = (t * 16 + c) * 64 + qq * 8;
  const int row0 = lane >> 3, inner = lane & 7;

#pragma unroll
  for (int m = 0; m < 2; ++m) {
    const float* X  = (m == 0) ? qin  : kin;
    const short* W  = (m == 0) ? Wq_b : Wk_b;
    const float* bb = (m == 0) ? bq   : bk;
    short* dst      = (m == 0) ? Qws  : Kws;

    bf16x8 a0 = cvt8(X + aoff);
    bf16x8 a1 = cvt8(X + aoff + 32);

#pragma unroll
    for (int nt = 0; nt < 4; ++nt) {
      f32x4 z = {0.f, 0.f, 0.f, 0.f};
      const short* wp = W + (nt * 16 + c) * 64 + qq * 8;
      bf16x8 b0 = *(const bf16x8*)(wp);
      bf16x8 b1 = *(const bf16x8*)(wp + 32);
      z = __builtin_amdgcn_mfma_f32_16x16x32_bf16(a0, b0, z, 0, 0, 0);
      z = __builtin_amdgcn_mfma_f32_16x16x32_bf16(a1, b1, z, 0, 0, 0);
      float bias = bb[nt * 16 + c];
#pragma unroll
      for (int r = 0; r < 4; ++r)           // C row = head = qq*4+r
        ldsT[w][qq * 4 + r][nt * 16 + c] = f2bf(z[r] + bias);
    }

    bf16x8 v0 = *(const bf16x8*)&ldsT[w][row0][inner * 8];
    bf16x8 v1 = *(const bf16x8*)&ldsT[w][row0 + 8][inner * 8];
    int bh0 = b * NH + row0, bh1 = b * NH + row0 + 8;
    *(bf16x8*)(dst + (bh0 * NS + s) * 64 + inner * 8) = v0;
    *(bf16x8*)(dst + (bh1 * NS + s) * 64 + inner * 8) = v1;
  }
}

// ---------------------------------------------------------------------------
// Kernel 1b: V projection + 64x64 transpose. Block = 4 waves, wave = 16 tokens.
// ---------------------------------------------------------------------------
__global__ __launch_bounds__(256) void vproj(
    const float* __restrict__ vin, const short* __restrict__ Wv_b,
    const float* __restrict__ bv, short* __restrict__ Vt)
{
  __shared__ __align__(16) short ldsVT[64][72];   // [d][token]
  const int tid = threadIdx.x;
  const int g = tid >> 6, lane = tid & 63;
  const int c = lane & 15, qq = lane >> 4;
  const int bh = blockIdx.x >> 5;
  const int stile = blockIdx.x & 31;
  const int b = bh >> 4, h = bh & 15;
  const int sb = stile * 64;

  bf16x8 wv[8];
  float bias[4];
#pragma unroll
  for (int nt = 0; nt < 4; ++nt) {
    const short* wp = Wv_b + (nt * 16 + c) * 64 + qq * 8;
    wv[nt * 2]     = *(const bf16x8*)(wp);
    wv[nt * 2 + 1] = *(const bf16x8*)(wp + 32);
    bias[nt] = bv[nt * 16 + c];
  }

  const float* ap = vin + ((size_t)((b * NS + sb + 16 * g + c) * 16 + h)) * 64 + qq * 8;
  bf16x8 a0 = cvt8(ap);
  bf16x8 a1 = cvt8(ap + 32);
#pragma unroll
  for (int nt = 0; nt < 4; ++nt) {
    f32x4 z = {0.f, 0.f, 0.f, 0.f};
    z = __builtin_amdgcn_mfma_f32_16x16x32_bf16(a0, wv[nt * 2], z, 0, 0, 0);
    z = __builtin_amdgcn_mfma_f32_16x16x32_bf16(a1, wv[nt * 2 + 1], z, 0, 0, 0);
    ushort4 u;
    u.x = (unsigned short)f2bf(z[0] + bias[nt]);
    u.y = (unsigned short)f2bf(z[1] + bias[nt]);
    u.z = (unsigned short)f2bf(z[2] + bias[nt]);
    u.w = (unsigned short)f2bf(z[3] + bias[nt]);
    *(ushort4*)&ldsVT[nt * 16 + c][16 * g + qq * 4] = u;   // token = 16g+qq*4+r
  }
  __syncthreads();

#pragma unroll
  for (int j = 0; j < 2; ++j) {
    int idx = tid + 256 * j;            // 0..511
    int d = idx >> 3, unit = idx & 7;
    bf16x8 o = *(const bf16x8*)&ldsVT[d][unit * 8];
    *(bf16x8*)(Vt + ((size_t)(bh * 64 + d)) * NS + sb + unit * 8) = o;
  }
}

// ---------------------------------------------------------------------------
// Kernel 2: pack mask int32 [B,1,S,S] -> bitwords [B*S, S/32]
// ---------------------------------------------------------------------------
__global__ __launch_bounds__(256) void pack_mask(const int* __restrict__ mask,
                                                 unsigned* __restrict__ mp)
{
  int idx = blockIdx.x * 256 + threadIdx.x;
  const int4* src = (const int4*)(mask + (long)idx * 32);
  unsigned w = 0;
#pragma unroll
  for (int i = 0; i < 8; ++i) {
    int4 v = src[i];
    w |= (v.x != 0 ? 1u : 0u) << (i * 4 + 0);
    w |= (v.y != 0 ? 1u : 0u) << (i * 4 + 1);
    w |= (v.z != 0 ? 1u : 0u) << (i * 4 + 2);
    w |= (v.w != 0 ? 1u : 0u) << (i * 4 + 3);
  }
  mp[idx] = w;
}

// ---------------------------------------------------------------------------
// Kernel 3: flash attention, m97-style cooperative LDS staging.
// Block = 4 waves, 128 q-rows of one (b,h); K-loop over 64-key tiles with
// double-buffered global_load_lds staging of K and V (XOR-swizzled on the
// global side so ds_read_b128 fragment reads are 2-way only = free).
// ---------------------------------------------------------------------------
__global__ __launch_bounds__(256) void attn(
    const short* __restrict__ Qws, const short* __restrict__ Kws,
    const short* __restrict__ Vt, const unsigned* __restrict__ Mp,
    short* __restrict__ AO)
{
  __shared__ __align__(16) short Ks[2][64][64];   // staged K tile (swizzled)
  __shared__ __align__(16) short Vs[2][64][64];   // staged V tile (swizzled)
  __shared__ __align__(16) short Ps[4][32][72];   // per-wave P transpose

  const int tid = threadIdx.x;
  const int w = tid >> 6, lane = tid & 63;
  const int c = lane & 15, qq = lane >> 4;
  const int bh = blockIdx.x >> 4;                 // 0..31
  const int qtile = blockIdx.x & 15;              // 0..15 (128 rows each)
  const int b = bh >> 4, h = bh & 15;
  const int qbase = qtile * 128 + w * 32;         // this wave's 32 rows

  const short* Qp = Qws + (size_t)bh * (NS * 64);
  const short* Kp = Kws + (size_t)bh * (NS * 64);
  const short* Vp = Vt + (size_t)bh * (64 * NS);
  const unsigned* mrow = Mp + (size_t)b * (NS * (NS / 32));

  const float C2 = 0.045084220f;                  // log2(e)/32

  // Q A-frags: 2 m-tiles x 2 k-halves, register-resident
  bf16x8 aq[2][2];
#pragma unroll
  for (int m = 0; m < 2; ++m) {
    const short* qp = Qp + (qbase + m * 16 + c) * 64 + qq * 8;
    aq[m][0] = *(const bf16x8*)(qp);
    aq[m][1] = *(const bf16x8*)(qp + 32);
  }

  float lsum[2][4];
  f32x4 O[2][4];
#pragma unroll
  for (int m = 0; m < 2; ++m)
#pragma unroll
    for (int r = 0; r < 4; ++r) lsum[m][r] = 0.f;
#pragma unroll
  for (int m = 0; m < 2; ++m)
#pragma unroll
    for (int dt = 0; dt < 4; ++dt) { f32x4 z = {0.f, 0.f, 0.f, 0.f}; O[m][dt] = z; }

  // staging lambda: wave w loads chunks j=w*2, w*2+1 of K and V (1KB each)
  const int srow = lane >> 3;                     // 0..7
  const int sunit = (lane & 7) ^ srow;            // XOR swizzle on global side
  auto stage = [&](int kt, int buf) {
#pragma unroll
    for (int i = 0; i < 2; ++i) {
      int j = w * 2 + i;
      const short* gk = Kp + ((size_t)(kt * 64 + j * 8 + srow)) * 64 + sunit * 8;
      gl_lds16(gk, &Ks[buf][0][0] + j * 512);
      const short* gv = Vp + ((size_t)(j * 8 + srow)) * NS + kt * 64 + sunit * 8;
      gl_lds16(gv, &Vs[buf][0][0] + j * 512);
    }
  };

  stage(0, 0);
  __syncthreads();

  for (int kt = 0; kt < NS / 64; ++kt) {
    const int buf = kt & 1;
    if (kt < NS / 64 - 1) stage(kt + 1, buf ^ 1);   // async prefetch

    // mask words for this tile: 8 (m,r) rows x 64 bits
    uint2 mw[2][4];
#pragma unroll
    for (int m = 0; m < 2; ++m)
#pragma unroll
      for (int r = 0; r < 4; ++r)
        mw[m][r] = *(const uint2*)(mrow +
            (size_t)(qbase + m * 16 + qq * 4 + r) * (NS / 32) + kt * 2);

    // QK^T: B-frags from swizzled LDS K, shared across m
    f32x4 st[2][4];
#pragma unroll
    for (int nt = 0; nt < 4; ++nt) {
      const short* kb = &Ks[buf][nt * 16 + c][0];
      bf16x8 b0 = *(const bf16x8*)(kb + ((qq ^ (c & 7)) << 3));
      bf16x8 b1 = *(const bf16x8*)(kb + (((4 + qq) ^ (c & 7)) << 3));
#pragma unroll
      for (int m = 0; m < 2; ++m) {
        f32x4 z = {0.f, 0.f, 0.f, 0.f};
        z = __builtin_amdgcn_mfma_f32_16x16x32_bf16(aq[m][0], b0, z, 0, 0, 0);
        z = __builtin_amdgcn_mfma_f32_16x16x32_bf16(aq[m][1], b1, z, 0, 0, 0);
        st[m][nt] = z;
      }
    }

    // masked exp (no max: |score/32| is O(1)), write P to wave-private LDS
#pragma unroll
    for (int m = 0; m < 2; ++m)
#pragma unroll
      for (int r = 0; r < 4; ++r) {
#pragma unroll
        for (int nt = 0; nt < 4; ++nt) {
          unsigned wsel = (nt & 2) ? mw[m][r].y : mw[m][r].x;
          int sh = ((nt & 1) << 4) + c;
          float e = ((wsel >> sh) & 1u)
                      ? __builtin_amdgcn_exp2f(st[m][nt][r] * C2) : 0.f;
          lsum[m][r] += e;
          Ps[w][m * 16 + qq * 4 + r][nt * 16 + c] = f2bf(e);
        }
      }

    // PV: A-frags of P (wave-private LDS), B-frags of V (swizzled LDS)
    bf16x8 ap[2][2];
#pragma unroll
    for (int m = 0; m < 2; ++m)
#pragma unroll
      for (int ks = 0; ks < 2; ++ks)
        ap[m][ks] = *(const bf16x8*)&Ps[w][m * 16 + c][ks * 32 + qq * 8];
#pragma unroll
    for (int ks = 0; ks < 2; ++ks)
#pragma unroll
      for (int dt = 0; dt < 4; ++dt) {
        const short* vb = &Vs[buf][dt * 16 + c][0];
        bf16x8 vf = *(const bf16x8*)(vb + ((((ks << 2) + qq) ^ (c & 7)) << 3));
#pragma unroll
        for (int m = 0; m < 2; ++m)
          O[m][dt] = __builtin_amdgcn_mfma_f32_16x16x32_bf16(ap[m][ks], vf, O[m][dt], 0, 0, 0);
      }

    __syncthreads();   // waves done with buf; prefetch (vmcnt) drained here
  }

  // normalize + store
#pragma unroll
  for (int m = 0; m < 2; ++m) {
    float inv[4];
#pragma unroll
    for (int r = 0; r < 4; ++r)
      inv[r] = 1.0f / fmaxf(rsum16(lsum[m][r]), 1e-30f);
#pragma unroll
    for (int dt = 0; dt < 4; ++dt)
#pragma unroll
      for (int r = 0; r < 4; ++r) {
        int row = qbase + m * 16 + qq * 4 + r;
        int col = h * 64 + dt * 16 + c;
        AO[((size_t)(b * NS + row)) * NHID + col] = f2bf(O[m][dt][r] * inv[r]);
      }
  }
}

// ---------------------------------------------------------------------------
// Kernel 4: output projection [4096,1024] x Wo^T + bo -> fp32 out.
// ---------------------------------------------------------------------------
__global__ __launch_bounds__(256) void oproj(
    const short* __restrict__ X, const short* __restrict__ Wo_b,
    const float* __restrict__ bo, float* __restrict__ out)
{
  const int tid = threadIdx.x;
  const int w = tid >> 6, lane = tid & 63;
  const int c = lane & 15, qq = lane >> 4;
  const int rt = blockIdx.x;
  const int cg = blockIdx.y;
  const int row0 = rt * 64 + w * 16;

  f32x4 acc[8];
#pragma unroll
  for (int nt = 0; nt < 8; ++nt) { f32x4 z = {0.f, 0.f, 0.f, 0.f}; acc[nt] = z; }

  const short* xp = X + (row0 + c) * NHID + qq * 8;
  for (int kb = 0; kb < NHID / 32; ++kb) {
    bf16x8 a = *(const bf16x8*)(xp + kb * 32);
#pragma unroll
    for (int nt = 0; nt < 8; ++nt) {
      bf16x8 bw = *(const bf16x8*)(Wo_b + (cg * 128 + nt * 16 + c) * NHID + kb * 32 + qq * 8);
      acc[nt] = __builtin_amdgcn_mfma_f32_16x16x32_bf16(a, bw, acc[nt], 0, 0, 0);
    }
  }

#pragma unroll
  for (int nt = 0; nt < 8; ++nt) {
    int col = cg * 128 + nt * 16 + c;
    float bias = bo[col];
#pragma unroll
    for (int r = 0; r < 4; ++r)
      out[(size_t)(row0 + qq * 4 + r) * NHID + col] = acc[nt][r] + bias;
  }
}

// ---------------------------------------------------------------------------
extern "C" void kernel_launch(void* const* d_in, const int* in_sizes, int n_in,
                              void* d_out, int out_size, void* d_ws, size_t ws_size,
                              hipStream_t stream) {
  const float* qin = (const float*)d_in[0];
  const float* kin = (const float*)d_in[1];
  const float* vin = (const float*)d_in[2];
  const int*  mask = (const int*)d_in[3];
  const float* Wq = (const float*)d_in[4];
  const float* bq = (const float*)d_in[5];
  const float* Wk = (const float*)d_in[6];
  const float* bk = (const float*)d_in[7];
  const float* Wv = (const float*)d_in[8];
  const float* bv = (const float*)d_in[9];
  const float* Wo = (const float*)d_in[10];
  const float* bo = (const float*)d_in[11];
  float* out = (float*)d_out;

  char* ws = (char*)d_ws;
  short* Qws = (short*)(ws);                           // 8 MB  [BH,S,64]
  short* Kws = (short*)(ws + (size_t)(8 << 20));       // 8 MB  [BH,S,64]
  short* Vt  = (short*)(ws + (size_t)(16 << 20));      // 8 MB  [BH,64,S]
  short* AO  = (short*)(ws + (size_t)(24 << 20));      // 8 MB  [B,S,HID]
  unsigned* Mp = (unsigned*)(ws + (size_t)(32 << 20)); // 1 MB packed mask
  short* Wo_b = (short*)(ws + (size_t)(33 << 20));     // 2 MB
  short* Wq_b = (short*)(ws + (size_t)(35 << 20));     // 8 KB
  short* Wk_b = (short*)(ws + (size_t)(35 << 20) + 8192);
  short* Wv_b = (short*)(ws + (size_t)(35 << 20) + 16384);

  cvt_w<<<1036, 256, 0, stream>>>(Wq, Wk, Wv, Wo, Wq_b, Wk_b, Wv_b, Wo_b);
  qk_proj<<<NB * NS / 4, 256, 0, stream>>>(qin, kin, Wq_b, bq, Wk_b, bk, Qws, Kws);
  vproj<<<(NB * NH) * (NS / 64), 256, 0, stream>>>(vin, Wv_b, bv, Vt);
  pack_mask<<<(NB * NS * (NS / 32)) / 256, 256, 0, stream>>>(mask, Mp);
  attn<<<(NB * NH) * (NS / 128), 256, 0, stream>>>(Qws, Kws, Vt, Mp, AO);
  oproj<<<dim3(64, 8), 256, 0, stream>>>(AO, Wo_b, bo, out);
}

// Round 6
// 283.241 us; speedup vs baseline: 1.8578x; 1.0838x over previous
//
#include <hip/hip_runtime.h>
#include <hip/hip_bf16.h>

#define NB 2
#define NS 2048
#define NH 16
#define ND 64
#define NHID 1024

// exp(x/32) = exp2(x * log2(e)/32) ; folded into Wq/bq at conversion time
#define QSCALE 0.045084220f

typedef __attribute__((ext_vector_type(8))) short bf16x8;
typedef __attribute__((ext_vector_type(4))) short s16x4;
typedef __attribute__((ext_vector_type(4))) float f32x4;

typedef __attribute__((address_space(3))) unsigned int lds_u32;
typedef __attribute__((address_space(1))) unsigned int glb_u32;

__device__ inline void gl_lds16(const void* g, void* l) {
  __builtin_amdgcn_global_load_lds((const glb_u32*)g, (lds_u32*)l, 16, 0, 0);
}

__device__ inline short f2bf(float f) {
  __hip_bfloat16 h = __float2bfloat16(f);
  short s; __builtin_memcpy(&s, &h, 2); return s;
}

__device__ inline bf16x8 cvt8(const float* __restrict__ p) {
  float4 x = *(const float4*)p;
  float4 y = *(const float4*)(p + 4);
  bf16x8 r;
  r[0] = f2bf(x.x); r[1] = f2bf(x.y); r[2] = f2bf(x.z); r[3] = f2bf(x.w);
  r[4] = f2bf(y.x); r[5] = f2bf(y.y); r[6] = f2bf(y.z); r[7] = f2bf(y.w);
  return r;
}

// ---------------------------------------------------------------------------
// Kernel 0: prep = pack_mask (blocks 0..1023) + weight cvt (blocks 1024..2059)
// Mask words = B*S*(S/32) = 262144 -> exactly 1024 blocks of 256.
// Wq additionally scaled by QSCALE (folds softmax scale + log2e into Q).
// ---------------------------------------------------------------------------
__global__ __launch_bounds__(256) void prep(
    const int* __restrict__ mask, unsigned* __restrict__ mp,
    const float* __restrict__ Wq, const float* __restrict__ Wk,
    const float* __restrict__ Wv, const float* __restrict__ Wo,
    short* __restrict__ Wq_b, short* __restrict__ Wk_b,
    short* __restrict__ Wv_b, short* __restrict__ Wo_b)
{
  if (blockIdx.x < 1024) {
    int idx = blockIdx.x * 256 + threadIdx.x;          // 0..262143
    const int4* src = (const int4*)(mask + (long)idx * 32);
    unsigned w = 0;
#pragma unroll
    for (int i = 0; i < 8; ++i) {
      int4 v = src[i];
      w |= (v.x != 0 ? 1u : 0u) << (i * 4 + 0);
      w |= (v.y != 0 ? 1u : 0u) << (i * 4 + 1);
      w |= (v.z != 0 ? 1u : 0u) << (i * 4 + 2);
      w |= (v.w != 0 ? 1u : 0u) << (i * 4 + 3);
    }
    mp[idx] = w;
  } else {
    int i = ((blockIdx.x - 1024) * 256 + threadIdx.x) * 4;  // 0..1060860
    const float* src; short* dst; int off; float sc = 1.0f;
    if (i < 1048576)      { src = Wo; dst = Wo_b; off = i; }
    else {
      int j = i - 1048576;
      if (j < 4096)       { src = Wq; dst = Wq_b; off = j; sc = QSCALE; }
      else if (j < 8192)  { src = Wk; dst = Wk_b; off = j - 4096; }
      else                { src = Wv; dst = Wv_b; off = j - 8192; }
    }
    float4 v = *(const float4*)(src + off);
    s16x4 o;
    o[0] = f2bf(v.x * sc); o[1] = f2bf(v.y * sc);
    o[2] = f2bf(v.z * sc); o[3] = f2bf(v.w * sc);
    *(s16x4*)(dst + off) = o;
  }
}

// ---------------------------------------------------------------------------
// Kernel 1: Q,K projection. Block = 4 waves, wave = 1 token (16 heads).
// Q path pre-scaled by QSCALE (weights + bias).
// ---------------------------------------------------------------------------
__global__ __launch_bounds__(256) void qk_proj(
    const float* __restrict__ qin, const float* __restrict__ kin,
    const short* __restrict__ Wq_b, const float* __restrict__ bq,
    const short* __restrict__ Wk_b, const float* __restrict__ bk,
    short* __restrict__ Qws, short* __restrict__ Kws)
{
  __shared__ __align__(16) short ldsT[4][16][72];
  const int tid = threadIdx.x;
  const int w = tid >> 6, lane = tid & 63;
  const int c = lane & 15, qq = lane >> 4;
  const int t = blockIdx.x * 4 + w;         // b*S + s
  const int b = t >> 11, s = t & (NS - 1);
  const int aoff = (t * 16 + c) * 64 + qq * 8;
  const int row0 = lane >> 3, inner = lane & 7;

#pragma unroll
  for (int m = 0; m < 2; ++m) {
    const float* X  = (m == 0) ? qin  : kin;
    const short* W  = (m == 0) ? Wq_b : Wk_b;
    const float* bb = (m == 0) ? bq   : bk;
    short* dst      = (m == 0) ? Qws  : Kws;
    const float bsc = (m == 0) ? QSCALE : 1.0f;

    bf16x8 a0 = cvt8(X + aoff);
    bf16x8 a1 = cvt8(X + aoff + 32);

#pragma unroll
    for (int nt = 0; nt < 4; ++nt) {
      f32x4 z = {0.f, 0.f, 0.f, 0.f};
      const short* wp = W + (nt * 16 + c) * 64 + qq * 8;
      bf16x8 b0 = *(const bf16x8*)(wp);
      bf16x8 b1 = *(const bf16x8*)(wp + 32);
      z = __builtin_amdgcn_mfma_f32_16x16x32_bf16(a0, b0, z, 0, 0, 0);
      z = __builtin_amdgcn_mfma_f32_16x16x32_bf16(a1, b1, z, 0, 0, 0);
      float bias = bb[nt * 16 + c] * bsc;
#pragma unroll
      for (int r = 0; r < 4; ++r)           // C row = head = qq*4+r
        ldsT[w][qq * 4 + r][nt * 16 + c] = f2bf(z[r] + bias);
    }

    bf16x8 v0 = *(const bf16x8*)&ldsT[w][row0][inner * 8];
    bf16x8 v1 = *(const bf16x8*)&ldsT[w][row0 + 8][inner * 8];
    int bh0 = b * NH + row0, bh1 = b * NH + row0 + 8;
    *(bf16x8*)(dst + (bh0 * NS + s) * 64 + inner * 8) = v0;
    *(bf16x8*)(dst + (bh1 * NS + s) * 64 + inner * 8) = v1;
  }
}

// ---------------------------------------------------------------------------
// Kernel 1b: V projection + 64x64 transpose. Block = 4 waves, wave = 16 tokens.
// ---------------------------------------------------------------------------
__global__ __launch_bounds__(256) void vproj(
    const float* __restrict__ vin, const short* __restrict__ Wv_b,
    const float* __restrict__ bv, short* __restrict__ Vt)
{
  __shared__ __align__(16) short ldsVT[64][72];   // [d][token]
  const int tid = threadIdx.x;
  const int g = tid >> 6, lane = tid & 63;
  const int c = lane & 15, qq = lane >> 4;
  const int bh = blockIdx.x >> 5;
  const int stile = blockIdx.x & 31;
  const int b = bh >> 4, h = bh & 15;
  const int sb = stile * 64;

  bf16x8 wv[8];
  float bias[4];
#pragma unroll
  for (int nt = 0; nt < 4; ++nt) {
    const short* wp = Wv_b + (nt * 16 + c) * 64 + qq * 8;
    wv[nt * 2]     = *(const bf16x8*)(wp);
    wv[nt * 2 + 1] = *(const bf16x8*)(wp + 32);
    bias[nt] = bv[nt * 16 + c];
  }

  const float* ap = vin + ((size_t)((b * NS + sb + 16 * g + c) * 16 + h)) * 64 + qq * 8;
  bf16x8 a0 = cvt8(ap);
  bf16x8 a1 = cvt8(ap + 32);
#pragma unroll
  for (int nt = 0; nt < 4; ++nt) {
    f32x4 z = {0.f, 0.f, 0.f, 0.f};
    z = __builtin_amdgcn_mfma_f32_16x16x32_bf16(a0, wv[nt * 2], z, 0, 0, 0);
    z = __builtin_amdgcn_mfma_f32_16x16x32_bf16(a1, wv[nt * 2 + 1], z, 0, 0, 0);
    ushort4 u;
    u.x = (unsigned short)f2bf(z[0] + bias[nt]);
    u.y = (unsigned short)f2bf(z[1] + bias[nt]);
    u.z = (unsigned short)f2bf(z[2] + bias[nt]);
    u.w = (unsigned short)f2bf(z[3] + bias[nt]);
    *(ushort4*)&ldsVT[nt * 16 + c][16 * g + qq * 4] = u;   // token = 16g+qq*4+r
  }
  __syncthreads();

#pragma unroll
  for (int j = 0; j < 2; ++j) {
    int idx = tid + 256 * j;            // 0..511
    int d = idx >> 3, unit = idx & 7;
    bf16x8 o = *(const bf16x8*)&ldsVT[d][unit * 8];
    *(bf16x8*)(Vt + ((size_t)(bh * 64 + d)) * NS + sb + unit * 8) = o;
  }
}

// ---------------------------------------------------------------------------
// Kernel 3: flash attention, transposed-score formulation.
// S^T = mfma(A=K, B=Q): lane holds 4 consecutive KEYS of one q-row ->
// packed b64 P writes, 2 mask words/iter, per-lane row sums.
// O^T = mfma(A=V^T, B=P^T): q stays in the lane-column -> no epilogue shuffle.
// XCD-swizzled grid; double-buffered global_load_lds staging of K and V.
// ---------------------------------------------------------------------------
__global__ __launch_bounds__(256) void attn(
    const short* __restrict__ Qws, const short* __restrict__ Kws,
    const short* __restrict__ Vt, const unsigned* __restrict__ Mp,
    short* __restrict__ AO)
{
  __shared__ __align__(16) short Ks[2][64][64];   // staged K tile (swizzled)
  __shared__ __align__(16) short Vs[2][64][64];   // staged V tile (swizzled)
  __shared__ __align__(16) short Ps[4][32][72];   // per-wave P^T tile [q][key]

  const int tid = threadIdx.x;
  const int w = tid >> 6, lane = tid & 63;
  const int c = lane & 15, qq = lane >> 4;
  const int bh = blockIdx.x & 31;                 // XCD swizzle: same bh -> same XCD
  const int qtile = blockIdx.x >> 5;              // 0..15
  const int b = bh >> 4, h = bh & 15;
  const int qbase = qtile * 128 + w * 32;         // this wave's 32 q-rows

  const short* Qp = Qws + (size_t)bh * (NS * 64);
  const short* Kp = Kws + (size_t)bh * (NS * 64);
  const short* Vp = Vt + (size_t)bh * (64 * NS);
  const unsigned* mrow = Mp + (size_t)b * (NS * (NS / 32));

  // Q B-frags: 2 q-tiles x 2 k-halves (pre-scaled by QSCALE in qk_proj)
  bf16x8 aq[2][2];
#pragma unroll
  for (int nq = 0; nq < 2; ++nq) {
    const short* qp = Qp + (qbase + nq * 16 + c) * 64 + qq * 8;
    aq[nq][0] = *(const bf16x8*)(qp);
    aq[nq][1] = *(const bf16x8*)(qp + 32);
  }

  float lsum[2] = {0.f, 0.f};                     // per-lane: q = qbase+nq*16+c
  f32x4 O[2][4];                                  // O^T: [nq][dt], reg = d
#pragma unroll
  for (int nq = 0; nq < 2; ++nq)
#pragma unroll
    for (int dt = 0; dt < 4; ++dt) { f32x4 z = {0.f, 0.f, 0.f, 0.f}; O[nq][dt] = z; }

  const int srow = lane >> 3;                     // 0..7
  const int sunit = (lane & 7) ^ srow;            // XOR swizzle on global side
  auto stage = [&](int kt, int buf) {
#pragma unroll
    for (int i = 0; i < 2; ++i) {
      int j = w * 2 + i;
      const short* gk = Kp + ((size_t)(kt * 64 + j * 8 + srow)) * 64 + sunit * 8;
      gl_lds16(gk, &Ks[buf][0][0] + j * 512);
      const short* gv = Vp + ((size_t)(j * 8 + srow)) * NS + kt * 64 + sunit * 8;
      gl_lds16(gv, &Vs[buf][0][0] + j * 512);
    }
  };

  stage(0, 0);
  __syncthreads();

  for (int kt = 0; kt < NS / 64; ++kt) {
    const int buf = kt & 1;
    if (kt < NS / 64 - 1) stage(kt + 1, buf ^ 1);   // async prefetch

    // mask: one 64-bit word per q-row (lane c owns its q)
    uint2 mw[2];
#pragma unroll
    for (int nq = 0; nq < 2; ++nq)
      mw[nq] = *(const uint2*)(mrow +
          (size_t)(qbase + nq * 16 + c) * (NS / 32) + kt * 2);

    // S^T = K·Q^T : A-frag from K (LDS), B-frag = Q (regs)
    // D[m=key][n=q]: lane col = q, regs = 4 consecutive keys (qq*4+r)
    f32x4 st[4][2];
#pragma unroll
    for (int mt = 0; mt < 4; ++mt) {
      const short* kb = &Ks[buf][mt * 16 + c][0];
      bf16x8 ak0 = *(const bf16x8*)(kb + ((qq ^ (c & 7)) << 3));
      bf16x8 ak1 = *(const bf16x8*)(kb + (((4 + qq) ^ (c & 7)) << 3));
#pragma unroll
      for (int nq = 0; nq < 2; ++nq) {
        f32x4 z = {0.f, 0.f, 0.f, 0.f};
        z = __builtin_amdgcn_mfma_f32_16x16x32_bf16(ak0, aq[nq][0], z, 0, 0, 0);
        z = __builtin_amdgcn_mfma_f32_16x16x32_bf16(ak1, aq[nq][1], z, 0, 0, 0);
        st[mt][nq] = z;
      }
    }

    // masked exp2 (scale pre-folded), packed b64 P^T writes (wave-private LDS)
#pragma unroll
    for (int mt = 0; mt < 4; ++mt) {
#pragma unroll
      for (int nq = 0; nq < 2; ++nq) {
        unsigned wsel = (mt & 2) ? mw[nq].y : mw[nq].x;
        unsigned nib = (wsel >> (((mt & 1) << 4) + (qq << 2))) & 0xFu;
        f32x4 s = st[mt][nq];
        float e0 = (nib & 1u) ? __builtin_amdgcn_exp2f(s[0]) : 0.f;
        float e1 = (nib & 2u) ? __builtin_amdgcn_exp2f(s[1]) : 0.f;
        float e2 = (nib & 4u) ? __builtin_amdgcn_exp2f(s[2]) : 0.f;
        float e3 = (nib & 8u) ? __builtin_amdgcn_exp2f(s[3]) : 0.f;
        lsum[nq] += (e0 + e1) + (e2 + e3);
        ushort4 u;
        u.x = (unsigned short)f2bf(e0);
        u.y = (unsigned short)f2bf(e1);
        u.z = (unsigned short)f2bf(e2);
        u.w = (unsigned short)f2bf(e3);
        *(ushort4*)&Ps[w][nq * 16 + c][mt * 16 + (qq << 2)] = u;
      }
    }

    // O^T += V^T · P : A-frag from Vs (d rows), B-frag = P^T from Ps
#pragma unroll
    for (int ks = 0; ks < 2; ++ks) {
      bf16x8 pf[2];
#pragma unroll
      for (int nq = 0; nq < 2; ++nq)
        pf[nq] = *(const bf16x8*)&Ps[w][nq * 16 + c][ks * 32 + qq * 8];
#pragma unroll
      for (int dt = 0; dt < 4; ++dt) {
        const short* vb = &Vs[buf][dt * 16 + c][0];
        bf16x8 vf = *(const bf16x8*)(vb + ((((ks << 2) + qq) ^ (c & 7)) << 3));
#pragma unroll
        for (int nq = 0; nq < 2; ++nq)
          O[nq][dt] = __builtin_amdgcn_mfma_f32_16x16x32_bf16(vf, pf[nq], O[nq][dt], 0, 0, 0);
      }
    }

    __syncthreads();   // waves done with buf; prefetch drained here
  }

  // reduce lsum across the 4 qq-groups (lanes c, c+16, c+32, c+48)
#pragma unroll
  for (int nq = 0; nq < 2; ++nq) {
    float v = lsum[nq];
    v += __shfl_xor(v, 16);
    v += __shfl_xor(v, 32);
    lsum[nq] = 1.0f / fmaxf(v, 1e-30f);
  }

  // store: lane holds q = qbase+nq*16+c, d = dt*16+qq*4+r -> b64 packed
#pragma unroll
  for (int nq = 0; nq < 2; ++nq) {
    int row = qbase + nq * 16 + c;
#pragma unroll
    for (int dt = 0; dt < 4; ++dt) {
      ushort4 u;
      u.x = (unsigned short)f2bf(O[nq][dt][0] * lsum[nq]);
      u.y = (unsigned short)f2bf(O[nq][dt][1] * lsum[nq]);
      u.z = (unsigned short)f2bf(O[nq][dt][2] * lsum[nq]);
      u.w = (unsigned short)f2bf(O[nq][dt][3] * lsum[nq]);
      *(ushort4*)(AO + ((size_t)(b * NS + row)) * NHID + h * 64 + dt * 16 + qq * 4) = u;
    }
  }
}

// ---------------------------------------------------------------------------
// Kernel 4: output projection [4096,1024] x Wo^T + bo -> fp32 out.
// ---------------------------------------------------------------------------
__global__ __launch_bounds__(256) void oproj(
    const short* __restrict__ X, const short* __restrict__ Wo_b,
    const float* __restrict__ bo, float* __restrict__ out)
{
  const int tid = threadIdx.x;
  const int w = tid >> 6, lane = tid & 63;
  const int c = lane & 15, qq = lane >> 4;
  const int rt = blockIdx.x;
  const int cg = blockIdx.y;
  const int row0 = rt * 64 + w * 16;

  f32x4 acc[8];
#pragma unroll
  for (int nt = 0; nt < 8; ++nt) { f32x4 z = {0.f, 0.f, 0.f, 0.f}; acc[nt] = z; }

  const short* xp = X + (row0 + c) * NHID + qq * 8;
  for (int kb = 0; kb < NHID / 32; ++kb) {
    bf16x8 a = *(const bf16x8*)(xp + kb * 32);
#pragma unroll
    for (int nt = 0; nt < 8; ++nt) {
      bf16x8 bw = *(const bf16x8*)(Wo_b + (cg * 128 + nt * 16 + c) * NHID + kb * 32 + qq * 8);
      acc[nt] = __builtin_amdgcn_mfma_f32_16x16x32_bf16(a, bw, acc[nt], 0, 0, 0);
    }
  }

#pragma unroll
  for (int nt = 0; nt < 8; ++nt) {
    int col = cg * 128 + nt * 16 + c;
    float bias = bo[col];
#pragma unroll
    for (int r = 0; r < 4; ++r)
      out[(size_t)(row0 + qq * 4 + r) * NHID + col] = acc[nt][r] + bias;
  }
}

// ---------------------------------------------------------------------------
extern "C" void kernel_launch(void* const* d_in, const int* in_sizes, int n_in,
                              void* d_out, int out_size, void* d_ws, size_t ws_size,
                              hipStream_t stream) {
  const float* qin = (const float*)d_in[0];
  const float* kin = (const float*)d_in[1];
  const float* vin = (const float*)d_in[2];
  const int*  mask = (const int*)d_in[3];
  const float* Wq = (const float*)d_in[4];
  const float* bq = (const float*)d_in[5];
  const float* Wk = (const float*)d_in[6];
  const float* bk = (const float*)d_in[7];
  const float* Wv = (const float*)d_in[8];
  const float* bv = (const float*)d_in[9];
  const float* Wo = (const float*)d_in[10];
  const float* bo = (const float*)d_in[11];
  float* out = (float*)d_out;

  char* ws = (char*)d_ws;
  short* Qws = (short*)(ws);                           // 8 MB  [BH,S,64]
  short* Kws = (short*)(ws + (size_t)(8 << 20));       // 8 MB  [BH,S,64]
  short* Vt  = (short*)(ws + (size_t)(16 << 20));      // 8 MB  [BH,64,S]
  short* AO  = (short*)(ws + (size_t)(24 << 20));      // 8 MB  [B,S,HID]
  unsigned* Mp = (unsigned*)(ws + (size_t)(32 << 20)); // 1 MB packed mask
  short* Wo_b = (short*)(ws + (size_t)(33 << 20));     // 2 MB
  short* Wq_b = (short*)(ws + (size_t)(35 << 20));     // 8 KB
  short* Wk_b = (short*)(ws + (size_t)(35 << 20) + 8192);
  short* Wv_b = (short*)(ws + (size_t)(35 << 20) + 16384);

  prep<<<2060, 256, 0, stream>>>(mask, Mp, Wq, Wk, Wv, Wo, Wq_b, Wk_b, Wv_b, Wo_b);
  qk_proj<<<NB * NS / 4, 256, 0, stream>>>(qin, kin, Wq_b, bq, Wk_b, bk, Qws, Kws);
  vproj<<<(NB * NH) * (NS / 64), 256, 0, stream>>>(vin, Wv_b, bv, Vt);
  attn<<<(NB * NH) * (NS / 128), 256, 0, stream>>>(Qws, Kws, Vt, Mp, AO);
  oproj<<<dim3(64, 8), 256, 0, stream>>>(AO, Wo_b, bo, out);
}

// Round 7
// 222.255 us; speedup vs baseline: 2.3675x; 1.2744x over previous
//
#include <hip/hip_runtime.h>
#include <hip/hip_bf16.h>

#define NB 2
#define NS 2048
#define NH 16
#define ND 64
#define NHID 1024

// exp(x/32) = exp2(x * log2(e)/32) ; folded into Wq/bq at conversion time
#define QSCALE 0.045084220f

typedef __attribute__((ext_vector_type(8))) short bf16x8;
typedef __attribute__((ext_vector_type(4))) short s16x4;
typedef __attribute__((ext_vector_type(4))) float f32x4;

typedef __attribute__((address_space(3))) unsigned int lds_u32;
typedef __attribute__((address_space(1))) unsigned int glb_u32;

__device__ inline void gl_lds16(const void* g, void* l) {
  __builtin_amdgcn_global_load_lds((const glb_u32*)g, (lds_u32*)l, 16, 0, 0);
}

__device__ inline short f2bf(float f) {
  __hip_bfloat16 h = __float2bfloat16(f);
  short s; __builtin_memcpy(&s, &h, 2); return s;
}

__device__ inline bf16x8 cvt8(const float* __restrict__ p) {
  float4 x = *(const float4*)p;
  float4 y = *(const float4*)(p + 4);
  bf16x8 r;
  r[0] = f2bf(x.x); r[1] = f2bf(x.y); r[2] = f2bf(x.z); r[3] = f2bf(x.w);
  r[4] = f2bf(y.x); r[5] = f2bf(y.y); r[6] = f2bf(y.z); r[7] = f2bf(y.w);
  return r;
}

// ---------------------------------------------------------------------------
// Kernel 0: prep = pack_mask (blocks 0..1023) + weight cvt (blocks 1024..2059)
// ---------------------------------------------------------------------------
__global__ __launch_bounds__(256) void prep(
    const int* __restrict__ mask, unsigned* __restrict__ mp,
    const float* __restrict__ Wq, const float* __restrict__ Wk,
    const float* __restrict__ Wv, const float* __restrict__ Wo,
    short* __restrict__ Wq_b, short* __restrict__ Wk_b,
    short* __restrict__ Wv_b, short* __restrict__ Wo_b)
{
  if (blockIdx.x < 1024) {
    int idx = blockIdx.x * 256 + threadIdx.x;          // 0..262143
    const int4* src = (const int4*)(mask + (long)idx * 32);
    unsigned w = 0;
#pragma unroll
    for (int i = 0; i < 8; ++i) {
      int4 v = src[i];
      w |= (v.x != 0 ? 1u : 0u) << (i * 4 + 0);
      w |= (v.y != 0 ? 1u : 0u) << (i * 4 + 1);
      w |= (v.z != 0 ? 1u : 0u) << (i * 4 + 2);
      w |= (v.w != 0 ? 1u : 0u) << (i * 4 + 3);
    }
    mp[idx] = w;
  } else {
    int i = ((blockIdx.x - 1024) * 256 + threadIdx.x) * 4;  // 0..1060860
    const float* src; short* dst; int off; float sc = 1.0f;
    if (i < 1048576)      { src = Wo; dst = Wo_b; off = i; }
    else {
      int j = i - 1048576;
      if (j < 4096)       { src = Wq; dst = Wq_b; off = j; sc = QSCALE; }
      else if (j < 8192)  { src = Wk; dst = Wk_b; off = j - 4096; }
      else                { src = Wv; dst = Wv_b; off = j - 8192; }
    }
    float4 v = *(const float4*)(src + off);
    s16x4 o;
    o[0] = f2bf(v.x * sc); o[1] = f2bf(v.y * sc);
    o[2] = f2bf(v.z * sc); o[3] = f2bf(v.w * sc);
    *(s16x4*)(dst + off) = o;
  }
}

// ---------------------------------------------------------------------------
// Kernel 1: Q,K projection. Block = 4 waves, wave = 1 token (16 heads).
// ---------------------------------------------------------------------------
__global__ __launch_bounds__(256) void qk_proj(
    const float* __restrict__ qin, const float* __restrict__ kin,
    const short* __restrict__ Wq_b, const float* __restrict__ bq,
    const short* __restrict__ Wk_b, const float* __restrict__ bk,
    short* __restrict__ Qws, short* __restrict__ Kws)
{
  __shared__ __align__(16) short ldsT[4][16][72];
  const int tid = threadIdx.x;
  const int w = tid >> 6, lane = tid & 63;
  const int c = lane & 15, qq = lane >> 4;
  const int t = blockIdx.x * 4 + w;         // b*S + s
  const int b = t >> 11, s = t & (NS - 1);
  const int aoff = (t * 16 + c) * 64 + qq * 8;
  const int row0 = lane >> 3, inner = lane & 7;

#pragma unroll
  for (int m = 0; m < 2; ++m) {
    const float* X  = (m == 0) ? qin  : kin;
    const short* W  = (m == 0) ? Wq_b : Wk_b;
    const float* bb = (m == 0) ? bq   : bk;
    short* dst      = (m == 0) ? Qws  : Kws;
    const float bsc = (m == 0) ? QSCALE : 1.0f;

    bf16x8 a0 = cvt8(X + aoff);
    bf16x8 a1 = cvt8(X + aoff + 32);

#pragma unroll
    for (int nt = 0; nt < 4; ++nt) {
      f32x4 z = {0.f, 0.f, 0.f, 0.f};
      const short* wp = W + (nt * 16 + c) * 64 + qq * 8;
      bf16x8 b0 = *(const bf16x8*)(wp);
      bf16x8 b1 = *(const bf16x8*)(wp + 32);
      z = __builtin_amdgcn_mfma_f32_16x16x32_bf16(a0, b0, z, 0, 0, 0);
      z = __builtin_amdgcn_mfma_f32_16x16x32_bf16(a1, b1, z, 0, 0, 0);
      float bias = bb[nt * 16 + c] * bsc;
#pragma unroll
      for (int r = 0; r < 4; ++r)           // C row = head = qq*4+r
        ldsT[w][qq * 4 + r][nt * 16 + c] = f2bf(z[r] + bias);
    }

    bf16x8 v0 = *(const bf16x8*)&ldsT[w][row0][inner * 8];
    bf16x8 v1 = *(const bf16x8*)&ldsT[w][row0 + 8][inner * 8];
    int bh0 = b * NH + row0, bh1 = b * NH + row0 + 8;
    *(bf16x8*)(dst + (bh0 * NS + s) * 64 + inner * 8) = v0;
    *(bf16x8*)(dst + (bh1 * NS + s) * 64 + inner * 8) = v1;
  }
}

// ---------------------------------------------------------------------------
// Kernel 1b: V projection + 64x64 transpose. Block = 4 waves, wave = 16 tokens.
// ---------------------------------------------------------------------------
__global__ __launch_bounds__(256) void vproj(
    const float* __restrict__ vin, const short* __restrict__ Wv_b,
    const float* __restrict__ bv, short* __restrict__ Vt)
{
  __shared__ __align__(16) short ldsVT[64][72];   // [d][token]
  const int tid = threadIdx.x;
  const int g = tid >> 6, lane = tid & 63;
  const int c = lane & 15, qq = lane >> 4;
  const int bh = blockIdx.x >> 5;
  const int stile = blockIdx.x & 31;
  const int b = bh >> 4, h = bh & 15;
  const int sb = stile * 64;

  bf16x8 wv[8];
  float bias[4];
#pragma unroll
  for (int nt = 0; nt < 4; ++nt) {
    const short* wp = Wv_b + (nt * 16 + c) * 64 + qq * 8;
    wv[nt * 2]     = *(const bf16x8*)(wp);
    wv[nt * 2 + 1] = *(const bf16x8*)(wp + 32);
    bias[nt] = bv[nt * 16 + c];
  }

  const float* ap = vin + ((size_t)((b * NS + sb + 16 * g + c) * 16 + h)) * 64 + qq * 8;
  bf16x8 a0 = cvt8(ap);
  bf16x8 a1 = cvt8(ap + 32);
#pragma unroll
  for (int nt = 0; nt < 4; ++nt) {
    f32x4 z = {0.f, 0.f, 0.f, 0.f};
    z = __builtin_amdgcn_mfma_f32_16x16x32_bf16(a0, wv[nt * 2], z, 0, 0, 0);
    z = __builtin_amdgcn_mfma_f32_16x16x32_bf16(a1, wv[nt * 2 + 1], z, 0, 0, 0);
    ushort4 u;
    u.x = (unsigned short)f2bf(z[0] + bias[nt]);
    u.y = (unsigned short)f2bf(z[1] + bias[nt]);
    u.z = (unsigned short)f2bf(z[2] + bias[nt]);
    u.w = (unsigned short)f2bf(z[3] + bias[nt]);
    *(ushort4*)&ldsVT[nt * 16 + c][16 * g + qq * 4] = u;   // token = 16g+qq*4+r
  }
  __syncthreads();

#pragma unroll
  for (int j = 0; j < 2; ++j) {
    int idx = tid + 256 * j;            // 0..511
    int d = idx >> 3, unit = idx & 7;
    bf16x8 o = *(const bf16x8*)&ldsVT[d][unit * 8];
    *(bf16x8*)(Vt + ((size_t)(bh * 64 + d)) * NS + sb + unit * 8) = o;
  }
}

// ---------------------------------------------------------------------------
// Kernel 3: flash attention, transposed-score formulation (unchanged).
// ---------------------------------------------------------------------------
__global__ __launch_bounds__(256) void attn(
    const short* __restrict__ Qws, const short* __restrict__ Kws,
    const short* __restrict__ Vt, const unsigned* __restrict__ Mp,
    short* __restrict__ AO)
{
  __shared__ __align__(16) short Ks[2][64][64];   // staged K tile (swizzled)
  __shared__ __align__(16) short Vs[2][64][64];   // staged V tile (swizzled)
  __shared__ __align__(16) short Ps[4][32][72];   // per-wave P^T tile [q][key]

  const int tid = threadIdx.x;
  const int w = tid >> 6, lane = tid & 63;
  const int c = lane & 15, qq = lane >> 4;
  const int bh = blockIdx.x & 31;                 // XCD swizzle
  const int qtile = blockIdx.x >> 5;              // 0..15
  const int b = bh >> 4, h = bh & 15;
  const int qbase = qtile * 128 + w * 32;

  const short* Qp = Qws + (size_t)bh * (NS * 64);
  const short* Kp = Kws + (size_t)bh * (NS * 64);
  const short* Vp = Vt + (size_t)bh * (64 * NS);
  const unsigned* mrow = Mp + (size_t)b * (NS * (NS / 32));

  bf16x8 aq[2][2];
#pragma unroll
  for (int nq = 0; nq < 2; ++nq) {
    const short* qp = Qp + (qbase + nq * 16 + c) * 64 + qq * 8;
    aq[nq][0] = *(const bf16x8*)(qp);
    aq[nq][1] = *(const bf16x8*)(qp + 32);
  }

  float lsum[2] = {0.f, 0.f};
  f32x4 O[2][4];
#pragma unroll
  for (int nq = 0; nq < 2; ++nq)
#pragma unroll
    for (int dt = 0; dt < 4; ++dt) { f32x4 z = {0.f, 0.f, 0.f, 0.f}; O[nq][dt] = z; }

  const int srow = lane >> 3;
  const int sunit = (lane & 7) ^ srow;
  auto stage = [&](int kt, int buf) {
#pragma unroll
    for (int i = 0; i < 2; ++i) {
      int j = w * 2 + i;
      const short* gk = Kp + ((size_t)(kt * 64 + j * 8 + srow)) * 64 + sunit * 8;
      gl_lds16(gk, &Ks[buf][0][0] + j * 512);
      const short* gv = Vp + ((size_t)(j * 8 + srow)) * NS + kt * 64 + sunit * 8;
      gl_lds16(gv, &Vs[buf][0][0] + j * 512);
    }
  };

  stage(0, 0);
  __syncthreads();

  for (int kt = 0; kt < NS / 64; ++kt) {
    const int buf = kt & 1;
    if (kt < NS / 64 - 1) stage(kt + 1, buf ^ 1);

    uint2 mw[2];
#pragma unroll
    for (int nq = 0; nq < 2; ++nq)
      mw[nq] = *(const uint2*)(mrow +
          (size_t)(qbase + nq * 16 + c) * (NS / 32) + kt * 2);

    f32x4 st[4][2];
#pragma unroll
    for (int mt = 0; mt < 4; ++mt) {
      const short* kb = &Ks[buf][mt * 16 + c][0];
      bf16x8 ak0 = *(const bf16x8*)(kb + ((qq ^ (c & 7)) << 3));
      bf16x8 ak1 = *(const bf16x8*)(kb + (((4 + qq) ^ (c & 7)) << 3));
#pragma unroll
      for (int nq = 0; nq < 2; ++nq) {
        f32x4 z = {0.f, 0.f, 0.f, 0.f};
        z = __builtin_amdgcn_mfma_f32_16x16x32_bf16(ak0, aq[nq][0], z, 0, 0, 0);
        z = __builtin_amdgcn_mfma_f32_16x16x32_bf16(ak1, aq[nq][1], z, 0, 0, 0);
        st[mt][nq] = z;
      }
    }

#pragma unroll
    for (int mt = 0; mt < 4; ++mt) {
#pragma unroll
      for (int nq = 0; nq < 2; ++nq) {
        unsigned wsel = (mt & 2) ? mw[nq].y : mw[nq].x;
        unsigned nib = (wsel >> (((mt & 1) << 4) + (qq << 2))) & 0xFu;
        f32x4 s = st[mt][nq];
        float e0 = (nib & 1u) ? __builtin_amdgcn_exp2f(s[0]) : 0.f;
        float e1 = (nib & 2u) ? __builtin_amdgcn_exp2f(s[1]) : 0.f;
        float e2 = (nib & 4u) ? __builtin_amdgcn_exp2f(s[2]) : 0.f;
        float e3 = (nib & 8u) ? __builtin_amdgcn_exp2f(s[3]) : 0.f;
        lsum[nq] += (e0 + e1) + (e2 + e3);
        ushort4 u;
        u.x = (unsigned short)f2bf(e0);
        u.y = (unsigned short)f2bf(e1);
        u.z = (unsigned short)f2bf(e2);
        u.w = (unsigned short)f2bf(e3);
        *(ushort4*)&Ps[w][nq * 16 + c][mt * 16 + (qq << 2)] = u;
      }
    }

#pragma unroll
    for (int ks = 0; ks < 2; ++ks) {
      bf16x8 pf[2];
#pragma unroll
      for (int nq = 0; nq < 2; ++nq)
        pf[nq] = *(const bf16x8*)&Ps[w][nq * 16 + c][ks * 32 + qq * 8];
#pragma unroll
      for (int dt = 0; dt < 4; ++dt) {
        const short* vb = &Vs[buf][dt * 16 + c][0];
        bf16x8 vf = *(const bf16x8*)(vb + ((((ks << 2) + qq) ^ (c & 7)) << 3));
#pragma unroll
        for (int nq = 0; nq < 2; ++nq)
          O[nq][dt] = __builtin_amdgcn_mfma_f32_16x16x32_bf16(vf, pf[nq], O[nq][dt], 0, 0, 0);
      }
    }

    __syncthreads();
  }

#pragma unroll
  for (int nq = 0; nq < 2; ++nq) {
    float v = lsum[nq];
    v += __shfl_xor(v, 16);
    v += __shfl_xor(v, 32);
    lsum[nq] = 1.0f / fmaxf(v, 1e-30f);
  }

#pragma unroll
  for (int nq = 0; nq < 2; ++nq) {
    int row = qbase + nq * 16 + c;
#pragma unroll
    for (int dt = 0; dt < 4; ++dt) {
      ushort4 u;
      u.x = (unsigned short)f2bf(O[nq][dt][0] * lsum[nq]);
      u.y = (unsigned short)f2bf(O[nq][dt][1] * lsum[nq]);
      u.z = (unsigned short)f2bf(O[nq][dt][2] * lsum[nq]);
      u.w = (unsigned short)f2bf(O[nq][dt][3] * lsum[nq]);
      *(ushort4*)(AO + ((size_t)(b * NS + row)) * NHID + h * 64 + dt * 16 + qq * 4) = u;
    }
  }
}

// ---------------------------------------------------------------------------
// Kernel 4: output projection, m97-style staged GEMM.
// Tile 64 rows x 128 cols per block (grid 64x8 = 512 = 2 blocks/CU), BK=64.
// Double-buffered global_load_lds staging of A (AO 64x64) and B (Wo 128x64)
// with the attn-verified XOR swizzle. Wave = 32x64 quadrant: acc 2x4 tiles.
// ---------------------------------------------------------------------------
__global__ __launch_bounds__(256, 2) void oproj(
    const short* __restrict__ X, const short* __restrict__ Wo_b,
    const float* __restrict__ bo, float* __restrict__ out)
{
  __shared__ __align__(16) short As[2][64][64];    // 16 KB
  __shared__ __align__(16) short Bs[2][128][64];   // 32 KB
  const int tid = threadIdx.x;
  const int w = tid >> 6, lane = tid & 63;
  const int c = lane & 15, qq = lane >> 4;
  const int rowbase = blockIdx.x * 64;             // 0..63 row tiles
  const int colbase = blockIdx.y * 128;            // 0..7 col tiles
  const int mh = w & 1, nh = w >> 1;               // wave quadrant

  const int srow = lane >> 3;
  const int sunit = (lane & 7) ^ srow;             // XOR swizzle (global side)

  auto stage = [&](int kb, int buf) {
#pragma unroll
    for (int i = 0; i < 6; ++i) {                  // 24 insts / 4 waves
      int t = w * 6 + i;
      if (t < 8) {                                 // A: 64 rows x 64 shorts
        const short* g = X + (size_t)(rowbase + t * 8 + srow) * NHID
                           + kb * 64 + sunit * 8;
        gl_lds16(g, &As[buf][0][0] + t * 512);
      } else {                                     // B: 128 rows x 64 shorts
        int j = t - 8;
        const short* g = Wo_b + (size_t)(colbase + j * 8 + srow) * NHID
                              + kb * 64 + sunit * 8;
        gl_lds16(g, &Bs[buf][0][0] + j * 512);
      }
    }
  };

  f32x4 acc[2][4];
#pragma unroll
  for (int mt = 0; mt < 2; ++mt)
#pragma unroll
    for (int nt = 0; nt < 4; ++nt) { f32x4 z = {0.f, 0.f, 0.f, 0.f}; acc[mt][nt] = z; }

  stage(0, 0);
  __syncthreads();

  for (int kb = 0; kb < NHID / 64; ++kb) {
    const int buf = kb & 1;
    if (kb < NHID / 64 - 1) stage(kb + 1, buf ^ 1);

    bf16x8 af[2][2];
#pragma unroll
    for (int mt = 0; mt < 2; ++mt) {
      const short* ap = &As[buf][mh * 32 + mt * 16 + c][0];
#pragma unroll
      for (int ks = 0; ks < 2; ++ks)
        af[mt][ks] = *(const bf16x8*)(ap + ((((ks << 2) + qq) ^ (c & 7)) << 3));
    }
#pragma unroll
    for (int nt = 0; nt < 4; ++nt) {
      const short* bp = &Bs[buf][nh * 64 + nt * 16 + c][0];
#pragma unroll
      for (int ks = 0; ks < 2; ++ks) {
        bf16x8 bf = *(const bf16x8*)(bp + ((((ks << 2) + qq) ^ (c & 7)) << 3));
#pragma unroll
        for (int mt = 0; mt < 2; ++mt)
          acc[mt][nt] = __builtin_amdgcn_mfma_f32_16x16x32_bf16(af[mt][ks], bf, acc[mt][nt], 0, 0, 0);
      }
    }

    __syncthreads();
  }

#pragma unroll
  for (int nt = 0; nt < 4; ++nt) {
    int col = colbase + nh * 64 + nt * 16 + c;
    float bias = bo[col];
#pragma unroll
    for (int mt = 0; mt < 2; ++mt) {
      int row = rowbase + mh * 32 + mt * 16 + qq * 4;
#pragma unroll
      for (int r = 0; r < 4; ++r)
        out[(size_t)(row + r) * NHID + col] = acc[mt][nt][r] + bias;
    }
  }
}

// ---------------------------------------------------------------------------
extern "C" void kernel_launch(void* const* d_in, const int* in_sizes, int n_in,
                              void* d_out, int out_size, void* d_ws, size_t ws_size,
                              hipStream_t stream) {
  const float* qin = (const float*)d_in[0];
  const float* kin = (const float*)d_in[1];
  const float* vin = (const float*)d_in[2];
  const int*  mask = (const int*)d_in[3];
  const float* Wq = (const float*)d_in[4];
  const float* bq = (const float*)d_in[5];
  const float* Wk = (const float*)d_in[6];
  const float* bk = (const float*)d_in[7];
  const float* Wv = (const float*)d_in[8];
  const float* bv = (const float*)d_in[9];
  const float* Wo = (const float*)d_in[10];
  const float* bo = (const float*)d_in[11];
  float* out = (float*)d_out;

  char* ws = (char*)d_ws;
  short* Qws = (short*)(ws);                           // 8 MB  [BH,S,64]
  short* Kws = (short*)(ws + (size_t)(8 << 20));       // 8 MB  [BH,S,64]
  short* Vt  = (short*)(ws + (size_t)(16 << 20));      // 8 MB  [BH,64,S]
  short* AO  = (short*)(ws + (size_t)(24 << 20));      // 8 MB  [B,S,HID]
  unsigned* Mp = (unsigned*)(ws + (size_t)(32 << 20)); // 1 MB packed mask
  short* Wo_b = (short*)(ws + (size_t)(33 << 20));     // 2 MB
  short* Wq_b = (short*)(ws + (size_t)(35 << 20));     // 8 KB
  short* Wk_b = (short*)(ws + (size_t)(35 << 20) + 8192);
  short* Wv_b = (short*)(ws + (size_t)(35 << 20) + 16384);

  prep<<<2060, 256, 0, stream>>>(mask, Mp, Wq, Wk, Wv, Wo, Wq_b, Wk_b, Wv_b, Wo_b);
  qk_proj<<<NB * NS / 4, 256, 0, stream>>>(qin, kin, Wq_b, bq, Wk_b, bk, Qws, Kws);
  vproj<<<(NB * NH) * (NS / 64), 256, 0, stream>>>(vin, Wv_b, bv, Vt);
  attn<<<(NB * NH) * (NS / 128), 256, 0, stream>>>(Qws, Kws, Vt, Mp, AO);
  oproj<<<dim3(64, 8), 256, 0, stream>>>(AO, Wo_b, bo, out);
}